// Round 6
// baseline (1124.928 us; speedup 1.0000x reference)
//
#include <hip/hip_runtime.h>
#include <math.h>

#define DIMC 128
#define FINC 78
#define REPW 1152        // 9 * 128
#define SCAN_TILE 1024   // elements per scan tile (256 threads x 4)

typedef __attribute__((ext_vector_type(8))) short short8x;
typedef __attribute__((ext_vector_type(4))) float f32x4;
typedef unsigned int u32;
typedef const __attribute__((address_space(1))) u32* gas_u32p;
typedef __attribute__((address_space(3))) u32* las_u32p;

__device__ inline float b2f(unsigned short u) {
    union { unsigned int i; float f; } v; v.i = ((unsigned int)u) << 16; return v.f;
}
__device__ inline unsigned short f2b(float f) {
    union { float f; unsigned int i; } v; v.f = f;
    unsigned int r = (v.i + 0x7FFFu + ((v.i >> 16) & 1u)) >> 16;
    return (unsigned short)r;
}

// 16B global -> LDS DMA (dest = wave-uniform base + lane*16; our dest is linear in tid).
__device__ __forceinline__ void gld16(const void* g, void* l) {
    __builtin_amdgcn_global_load_lds((gas_u32p)g, (las_u32p)l, 16, 0, 0);
}

// ---------------- setup kernels ----------------

__global__ void k_fill_int(int* __restrict__ p, int v, int n) {
    int i = blockIdx.x * blockDim.x + threadIdx.x;
    if (i < n) p[i] = v;
}

__global__ void k_fill(float* __restrict__ p, float v, int n) {
    int i = blockIdx.x * blockDim.x + threadIdx.x;
    if (i < n) p[i] = v;
}

__global__ void k_count(const int* __restrict__ dst, int* __restrict__ cnt, int E) {
    int e = blockIdx.x * blockDim.x + threadIdx.x;
    if (e < E) atomicAdd(&cnt[dst[e]], 1);
}

__launch_bounds__(256)
__global__ void k_tilesum(const int* __restrict__ cnt, int* __restrict__ tileSum, int N) {
    __shared__ int red[256];
    int base = blockIdx.x * SCAN_TILE;
    int s = 0;
    for (int i = threadIdx.x; i < SCAN_TILE; i += 256) {
        int idx = base + i;
        if (idx < N) s += cnt[idx];
    }
    red[threadIdx.x] = s;
    __syncthreads();
    for (int d = 128; d > 0; d >>= 1) {
        if (threadIdx.x < d) red[threadIdx.x] += red[threadIdx.x + d];
        __syncthreads();
    }
    if (threadIdx.x == 0) tileSum[blockIdx.x] = red[0];
}

__launch_bounds__(256)
__global__ void k_tilescan(const int* __restrict__ tileSum, int* __restrict__ tileOff,
                           int* __restrict__ rowptr, int T, int N) {
    __shared__ int sh[256];
    int t = threadIdx.x;
    int orig = (t < T) ? tileSum[t] : 0;
    sh[t] = orig;
    __syncthreads();
    for (int d = 1; d < 256; d <<= 1) {
        int v = (t >= d) ? sh[t - d] : 0;
        __syncthreads();
        sh[t] += v;
        __syncthreads();
    }
    if (t < T) tileOff[t] = sh[t] - orig;
    if (t == 255) rowptr[N] = sh[255];
}

__launch_bounds__(256)
__global__ void k_tileemit(const int* __restrict__ cnt, const int* __restrict__ tileOff,
                           int* __restrict__ rowptr, int* __restrict__ cursor,
                           float* __restrict__ dis, int N) {
    __shared__ int sh[256];
    int t = threadIdx.x;
    int base = blockIdx.x * SCAN_TILE;
    int idx0 = base + t * 4;
    int v0 = 0, v1 = 0, v2 = 0, v3 = 0;
    if (idx0 + 3 < N) {
        int4 v = *(const int4*)(cnt + idx0);
        v0 = v.x; v1 = v.y; v2 = v.z; v3 = v.w;
    } else {
        if (idx0 + 0 < N) v0 = cnt[idx0 + 0];
        if (idx0 + 1 < N) v1 = cnt[idx0 + 1];
        if (idx0 + 2 < N) v2 = cnt[idx0 + 2];
        if (idx0 + 3 < N) v3 = cnt[idx0 + 3];
    }
    int s0 = v0, s1 = s0 + v1, s2 = s1 + v2, s3 = s2 + v3;
    sh[t] = s3;
    __syncthreads();
    for (int d = 1; d < 256; d <<= 1) {
        int v = (t >= d) ? sh[t - d] : 0;
        __syncthreads();
        sh[t] += v;
        __syncthreads();
    }
    int gbase = tileOff[blockIdx.x] + ((t == 0) ? 0 : sh[t - 1]);
    int ex[4] = {0, s0, s1, s2};
    int vv[4] = {v0, v1, v2, v3};
#pragma unroll
    for (int j = 0; j < 4; ++j) {
        int idx = idx0 + j;
        if (idx < N) {
            int r = gbase + ex[j];
            rowptr[idx] = r;
            cursor[idx] = r;
            dis[idx] = rsqrtf((float)vv[j] + 1.0f);
        }
    }
}

__global__ void k_scatter(const int* __restrict__ src, const int* __restrict__ dst,
                          int* __restrict__ cursor, int* __restrict__ col, int E) {
    int e = blockIdx.x * blockDim.x + threadIdx.x;
    if (e < E) {
        int pos = atomicAdd(&cursor[dst[e]], 1);
        col[pos] = src[e];
    }
}

__global__ void k_bounds(const int* __restrict__ batch, int* __restrict__ start, int N, int G) {
    int g = blockIdx.x * blockDim.x + threadIdx.x;
    if (g <= G) {
        int lo = 0, hi = N;
        while (lo < hi) { int mid = (lo + hi) >> 1; if (batch[mid] < g) lo = mid + 1; else hi = mid; }
        start[g] = lo;
    }
}

// ---------------- weight split: fp32 W[k][n] -> transposed bf16 hi/lo [n][k] ----------------

__global__ void k_cvt_w(const float* __restrict__ s0, const float* __restrict__ s1,
                        const float* __restrict__ s2, const float* __restrict__ s3,
                        const float* __restrict__ s4, const float* __restrict__ s5,
                        const float* __restrict__ s6, const float* __restrict__ s7,
                        unsigned short* __restrict__ whi, unsigned short* __restrict__ wlo) {
    int my = blockIdx.y;
    const float* src; int Ksrc, KP; size_t dstoff;
    const size_t o96 = (size_t)128 * 96, o128 = (size_t)128 * 128;
    switch (my) {
        case 0: src = s0; Ksrc = 78;  KP = 96;  dstoff = 0; break;
        case 1: src = s1; Ksrc = 78;  KP = 96;  dstoff = o96; break;
        case 2: src = s2; Ksrc = 128; KP = 128; dstoff = 2 * o96; break;
        case 3: src = s3; Ksrc = 128; KP = 128; dstoff = 2 * o96 + o128; break;
        case 4: src = s4; Ksrc = 128; KP = 128; dstoff = 2 * o96 + 2 * o128; break;
        case 5: src = s5; Ksrc = 128; KP = 128; dstoff = 2 * o96 + 3 * o128; break;
        case 6: src = s6; Ksrc = 128; KP = 128; dstoff = 2 * o96 + 4 * o128; break;
        default: src = s7; Ksrc = 128; KP = 128; dstoff = 2 * o96 + 5 * o128; break;
    }
    int i = blockIdx.x * blockDim.x + threadIdx.x;
    if (i < 128 * KP) {
        int n = i / KP, k = i - n * KP;
        float v = (k < Ksrc) ? src[(size_t)k * DIMC + n] : 0.f;
        unsigned short hi = f2b(v);
        unsigned short lo = f2b(v - b2f(hi));
        whi[dstoff + i] = hi;
        wlo[dstoff + i] = lo;
    }
}

// ---------------- pack x: fp32 [N][78] -> hi/lo planes [N][96] (zero-padded cols) ----------------

__global__ void k_pack_x(const float* __restrict__ x, unsigned short* __restrict__ xhi,
                         unsigned short* __restrict__ xlo, int N) {
    int i = blockIdx.x * blockDim.x + threadIdx.x;
    int r = i / 24, cc = (i - r * 24) * 4;
    if (r >= N) return;
    float v[4];
#pragma unroll
    for (int j = 0; j < 4; ++j) { int k = cc + j; v[j] = (k < FINC) ? x[(size_t)r * FINC + k] : 0.f; }
    unsigned short h[4], l[4];
#pragma unroll
    for (int j = 0; j < 4; ++j) { h[j] = f2b(v[j]); l[j] = f2b(v[j] - b2f(h[j])); }
    *(ushort4*)(xhi + (size_t)r * 96 + cc) = make_ushort4(h[0], h[1], h[2], h[3]);
    *(ushort4*)(xlo + (size_t)r * 96 + cc) = make_ushort4(l[0], l[1], l[2], l[3]);
}

// ---------------- streaming MFMA GEMM: B resident in LDS, barrier-free A stream ----------------
// B (whi/wlo [128 n][KP k]) is DMA-staged to LDS ONCE per block (proven source-XOR
// scheme: octet g of row r lives at LDS unit g^(r&3))*128+r of chunk plane).
// After one barrier, each wave independently processes 32-row A strips (grid-stride):
//   rows r0 = strip*32 + lm, r1 = r0 + 16 (lane lm=lane&15, octet q=lane>>4)
//   per 32-K chunk: A-frag loads (reg double-buffered, NO barriers/waits by hand),
//   8 column-tiles: 2 ds_read_b128 (bh, bl) reused for both row-groups, 6 MFMA.
// C = epi(A @ B^T): bias, relu, rowScale, optional col stats (reg-accumulated, reduced once).
// MFMA layout (HW-verified r4/r5): acc = mfma(b_frag, a_frag) -> C[row=lm][col=ct*16+q*4+i].

#define LOADA(c, H0, L0, H1, L1, F00, F01, F10, F11)                           \
    {                                                                          \
        const int ko_ = (c) * 32 + q * 8;                                      \
        if constexpr (SPLITA) {                                                \
            H0 = *(const short8x*)(aph0 + ko_);                                \
            L0 = *(const short8x*)(apl0 + ko_);                                \
            H1 = *(const short8x*)(aph1 + ko_);                                \
            L1 = *(const short8x*)(apl1 + ko_);                                \
        } else {                                                               \
            F00 = *(const float4*)(apf0 + ko_);                                \
            F01 = *(const float4*)(apf0 + ko_ + 4);                            \
            F10 = *(const float4*)(apf1 + ko_);                                \
            F11 = *(const float4*)(apf1 + ko_ + 4);                            \
        }                                                                      \
    }

#define CVT8(F0, F1, H, L)                                                     \
    {                                                                          \
        float ff_[8] = {F0.x, F0.y, F0.z, F0.w, F1.x, F1.y, F1.z, F1.w};       \
        _Pragma("unroll")                                                      \
        for (int j_ = 0; j_ < 8; ++j_) {                                       \
            unsigned short hh_ = f2b(ff_[j_]);                                 \
            H[j_] = (short)hh_;                                                \
            L[j_] = (short)f2b(ff_[j_] - b2f(hh_));                            \
        }                                                                      \
    }

#define EPI(ROW, ACC)                                                          \
    {                                                                          \
        const int row_ = (ROW);                                                \
        const bool valid_ = row_ < N;                                          \
        float sc_ = 1.f;                                                       \
        if (rowScale) sc_ = rowScale[valid_ ? row_ : 0];                       \
        _Pragma("unroll")                                                      \
        for (int ct_ = 0; ct_ < 8; ++ct_) {                                    \
            float vv_[4];                                                      \
            _Pragma("unroll")                                                  \
            for (int i_ = 0; i_ < 4; ++i_) {                                   \
                float v_ = ACC[ct_][i_];                                       \
                if (bias) v_ += bias[ct_ * 16 + q * 4 + i_];                   \
                if (doRelu) v_ = fmaxf(v_, 0.f);                               \
                v_ *= sc_;                                                     \
                vv_[i_] = valid_ ? v_ : 0.f;                                   \
                if constexpr (STATS) {                                         \
                    cs[ct_][i_] += vv_[i_];                                    \
                    cq[ct_][i_] = fmaf(vv_[i_], vv_[i_], cq[ct_][i_]);         \
                }                                                              \
            }                                                                  \
            if (valid_)                                                        \
                *(float4*)(C + (size_t)row_ * DIMC + ct_ * 16 + q * 4) =       \
                    make_float4(vv_[0], vv_[1], vv_[2], vv_[3]);               \
        }                                                                      \
    }

template<int KP, bool SPLITA, bool STATS>
__launch_bounds__(256, 2)
__global__ void k_gemm_s(const void* __restrict__ A0, const void* __restrict__ A1,
                         const unsigned short* __restrict__ Bhi, const unsigned short* __restrict__ Blo,
                         const float* __restrict__ bias, const float* __restrict__ rowScale,
                         float* __restrict__ statsOut, float* __restrict__ C,
                         int N, int doRelu, int nStrips) {
    constexpr int NT = KP / 32;
    __shared__ unsigned short lds[NT][2][4096];   // NT*16 KB: whole B hi/lo
    __shared__ float sStats[256];
    const int tid = threadIdx.x;
    const int wave = tid >> 6, lane = tid & 63;
    const int lm = lane & 15, q = lane >> 4;

    if constexpr (STATS) sStats[tid] = 0.f;

    // ---- stage ALL of B once (proven DMA + source-XOR scheme) ----
    {
        const int rr = tid & 127;
        const int g0 = tid >> 7;
        const int o0 = ((g0 ^ (rr & 3)) << 3);
        const int o1 = (((2 + g0) ^ (rr & 3)) << 3);
        const size_t brow = (size_t)rr * KP;
        const int u0 = tid << 3;
        const int u1 = (256 + tid) << 3;
#pragma unroll
        for (int c = 0; c < NT; ++c) {
            const int cb = c << 5;
            gld16(Bhi + brow + cb + o0, &lds[c][0][u0]);
            gld16(Bhi + brow + cb + o1, &lds[c][0][u1]);
            gld16(Blo + brow + cb + o0, &lds[c][1][u0]);
            gld16(Blo + brow + cb + o1, &lds[c][1][u1]);
        }
    }
    asm volatile("s_waitcnt vmcnt(0)" ::: "memory");
    __syncthreads();
    // ---- from here on: ZERO barriers, waves fully independent ----

    float cs[8][4], cq[8][4];
    if constexpr (STATS) {
#pragma unroll
        for (int a = 0; a < 8; ++a)
#pragma unroll
            for (int b = 0; b < 4; ++b) { cs[a][b] = 0.f; cq[a][b] = 0.f; }
    }

    const int gw = blockIdx.x * 4 + wave;
    const int nw = gridDim.x * 4;

    for (int s = gw; s < nStrips; s += nw) {
        const int r0 = s * 32 + lm, r1 = r0 + 16;
        const int a0 = (r0 < N) ? r0 : N - 1;
        const int a1 = (r1 < N) ? r1 : N - 1;
        const unsigned short *aph0 = nullptr, *apl0 = nullptr, *aph1 = nullptr, *apl1 = nullptr;
        const float *apf0 = nullptr, *apf1 = nullptr;
        if constexpr (SPLITA) {
            aph0 = (const unsigned short*)A0 + (size_t)a0 * KP;
            apl0 = (const unsigned short*)A1 + (size_t)a0 * KP;
            aph1 = (const unsigned short*)A0 + (size_t)a1 * KP;
            apl1 = (const unsigned short*)A1 + (size_t)a1 * KP;
        } else {
            apf0 = (const float*)A0 + (size_t)a0 * KP;
            apf1 = (const float*)A0 + (size_t)a1 * KP;
        }

        short8x xh0, xl0, xh1, xl1, yh0, yl0, yh1, yl1;
        float4 xf00, xf01, xf10, xf11, yf00, yf01, yf10, yf11;
        LOADA(0, xh0, xl0, xh1, xl1, xf00, xf01, xf10, xf11);

        f32x4 acc0[8], acc1[8];
#pragma unroll
        for (int i = 0; i < 8; ++i) {
            acc0[i] = (f32x4){0.f, 0.f, 0.f, 0.f};
            acc1[i] = (f32x4){0.f, 0.f, 0.f, 0.f};
        }

#pragma unroll
        for (int t = 0; t < NT; ++t) {
            if (t + 1 < NT) LOADA(t + 1, yh0, yl0, yh1, yl1, yf00, yf01, yf10, yf11);
            short8x ah0, al0, ah1, al1;
            if constexpr (SPLITA) {
                ah0 = xh0; al0 = xl0; ah1 = xh1; al1 = xl1;
            } else {
                CVT8(xf00, xf01, ah0, al0);
                CVT8(xf10, xf11, ah1, al1);
            }
#pragma unroll
            for (int ct = 0; ct < 8; ++ct) {
                int n = ct * 16 + lm;
                int sl = ((q ^ (n & 3)) * 128 + n) << 3;
                short8x bh = *(const short8x*)&lds[t][0][sl];
                short8x bl = *(const short8x*)&lds[t][1][sl];
                acc0[ct] = __builtin_amdgcn_mfma_f32_16x16x32_bf16(bh, ah0, acc0[ct], 0, 0, 0);
                acc0[ct] = __builtin_amdgcn_mfma_f32_16x16x32_bf16(bh, al0, acc0[ct], 0, 0, 0);
                acc0[ct] = __builtin_amdgcn_mfma_f32_16x16x32_bf16(bl, ah0, acc0[ct], 0, 0, 0);
                acc1[ct] = __builtin_amdgcn_mfma_f32_16x16x32_bf16(bh, ah1, acc1[ct], 0, 0, 0);
                acc1[ct] = __builtin_amdgcn_mfma_f32_16x16x32_bf16(bh, al1, acc1[ct], 0, 0, 0);
                acc1[ct] = __builtin_amdgcn_mfma_f32_16x16x32_bf16(bl, ah1, acc1[ct], 0, 0, 0);
            }
            if (t + 1 < NT) {
                xh0 = yh0; xl0 = yl0; xh1 = yh1; xl1 = yl1;
                xf00 = yf00; xf01 = yf01; xf10 = yf10; xf11 = yf11;
            }
        }

        EPI(r0, acc0);
        EPI(r1, acc1);
    }

    if constexpr (STATS) {
        __syncthreads();
#pragma unroll
        for (int ct = 0; ct < 8; ++ct)
#pragma unroll
            for (int i = 0; i < 4; ++i) {
                float vs = cs[ct][i], vq = cq[ct][i];
#pragma unroll
                for (int o = 1; o < 16; o <<= 1) { vs += __shfl_xor(vs, o); vq += __shfl_xor(vq, o); }
                if (lm == 0) {
                    int colg = ct * 16 + q * 4 + i;
                    atomicAdd(&sStats[colg], vs);
                    atomicAdd(&sStats[DIMC + colg], vq);
                }
            }
        __syncthreads();
        atomicAdd(&statsOut[tid], sStats[tid]);
    }
}

// ---------------- BN coefficients: sums -> (scale, shift) ----------------

__global__ void k_bn_coef(const float* __restrict__ bnsum, const float* __restrict__ gamma,
                          const float* __restrict__ beta, float* __restrict__ coef, float invN) {
    int c = threadIdx.x;  // 128
    float mu  = bnsum[c] * invN;
    float var = bnsum[128 + c] * invN - mu * mu;
    float inv = rsqrtf(var + 1e-5f);
    float s = gamma[c] * inv;
    coef[c] = s;
    coef[128 + c] = beta[c] - mu * s;
}

// ---- fold BN affine into next layer's W1: W'[n][k] = s[k]*w1[k][n], cvec[n] = sum_k t[k]*w1[k][n]

__global__ void k_fold_w(const float* __restrict__ w1, const float* __restrict__ coefL,
                         unsigned short* __restrict__ fwhi, unsigned short* __restrict__ fwlo,
                         float* __restrict__ cvec) {
    __shared__ float red[128];
    int n = blockIdx.x, k = threadIdx.x;
    float w = w1[(size_t)k * DIMC + n];
    float ws = w * coefL[k];
    unsigned short h = f2b(ws);
    fwhi[(size_t)n * DIMC + k] = h;
    fwlo[(size_t)n * DIMC + k] = f2b(ws - b2f(h));
    red[k] = w * coefL[DIMC + k];
    __syncthreads();
    for (int d = 64; d > 0; d >>= 1) { if (k < d) red[k] += red[k + d]; __syncthreads(); }
    if (k == 0) cvec[n] = red[0];
}

// ---------------- CSR gather aggregation (fp32) ----------------

__global__ void k_gather_gcn(const float4* __restrict__ t, const int* __restrict__ rowptr,
                             const int* __restrict__ col, const float* __restrict__ dis,
                             const float4* __restrict__ bias, float4* __restrict__ out, int N) {
    int i = blockIdx.x * blockDim.x + threadIdx.x;
    int node = i >> 5, c4 = i & 31;
    if (node >= N) return;
    int s = rowptr[node], e = rowptr[node + 1];
    float4 acc = t[(size_t)node * 32 + c4];
    for (int k = s; k < e; ++k) {
        float4 v = t[(size_t)col[k] * 32 + c4];
        acc.x += v.x; acc.y += v.y; acc.z += v.z; acc.w += v.w;
    }
    float d = dis[node];
    float4 b = bias[c4];
    float4 o;
    o.x = fmaxf(acc.x * d + b.x, 0.f);
    o.y = fmaxf(acc.y * d + b.y, 0.f);
    o.z = fmaxf(acc.z * d + b.z, 0.f);
    o.w = fmaxf(acc.w * d + b.w, 0.f);
    out[(size_t)node * 32 + c4] = o;
}

__global__ void k_gather_gin(const float4* __restrict__ t, const int* __restrict__ rowptr,
                             const int* __restrict__ col, const float4* __restrict__ bias,
                             float4* __restrict__ out, int N) {
    int i = blockIdx.x * blockDim.x + threadIdx.x;
    int node = i >> 5, c4 = i & 31;
    if (node >= N) return;
    int s = rowptr[node], e = rowptr[node + 1];
    float4 acc = t[(size_t)node * 32 + c4];
    for (int k = s; k < e; ++k) {
        float4 v = t[(size_t)col[k] * 32 + c4];
        acc.x += v.x; acc.y += v.y; acc.z += v.z; acc.w += v.w;
    }
    float4 b = bias[c4];
    float4 o;
    o.x = fmaxf(acc.x + b.x, 0.f);
    o.y = fmaxf(acc.y + b.y, 0.f);
    o.z = fmaxf(acc.z + b.z, 0.f);
    o.w = fmaxf(acc.w + b.w, 0.f);
    out[(size_t)node * 32 + c4] = o;
}

// ---------------- segment max (fp32) ----------------

__global__ void k_segmax_gin_all(const float* __restrict__ h0, const float* __restrict__ h1,
                                 const float* __restrict__ h2, const float* __restrict__ coef,
                                 const int* __restrict__ start, float* __restrict__ out) {
    int g = blockIdx.x, c = threadIdx.x;
    float s0 = coef[c],       t0 = coef[128 + c];
    float s1 = coef[256 + c], t1 = coef[384 + c];
    float s2 = coef[512 + c], t2 = coef[640 + c];
    int s = start[g], e = start[g + 1];
    float m0 = -INFINITY, m1 = -INFINITY, m2 = -INFINITY, mm = -INFINITY, me = -INFINITY;
    for (int n = s; n < e; ++n) {
        size_t idx = (size_t)n * DIMC + c;
        float a0 = fmaf(h0[idx], s0, t0);
        float a1 = fmaf(h1[idx], s1, t1);
        float a2 = fmaf(h2[idx], s2, t2);
        m0 = fmaxf(m0, a0); m1 = fmaxf(m1, a1); m2 = fmaxf(m2, a2);
        mm = fmaxf(mm, a0 * a1 * a2);
        me = fmaxf(me, a0 + a1 + a2);
    }
    size_t o = (size_t)g * REPW + c;
    out[o]            = m0;
    out[o + 1 * DIMC] = m1;
    out[o + 2 * DIMC] = m2;
    out[o + 3 * DIMC] = mm;
    out[o + 4 * DIMC] = me;
}

__global__ void k_segmax_gcn(const float* __restrict__ G1, const float* __restrict__ G2,
                             const int* __restrict__ start, float* __restrict__ out) {
    int g = blockIdx.x, c = threadIdx.x;
    int s = start[g], e = start[g + 1];
    float m1 = -INFINITY, m2 = -INFINITY, ma = -INFINITY, mm = -INFINITY;
    for (int n = s; n < e; ++n) {
        float a = G1[(size_t)n * DIMC + c], b = G2[(size_t)n * DIMC + c];
        m1 = fmaxf(m1, a); m2 = fmaxf(m2, b);
        ma = fmaxf(ma, a + b); mm = fmaxf(mm, a * b);
    }
    size_t o = (size_t)g * REPW + c;
    out[o + 5 * DIMC] = m1;
    out[o + 6 * DIMC] = m2;
    out[o + 7 * DIMC] = ma;
    out[o + 8 * DIMC] = mm;
}

// ---------------- launch ----------------

extern "C" void kernel_launch(void* const* d_in, const int* in_sizes, int n_in,
                              void* d_out, int out_size, void* d_ws, size_t ws_size,
                              hipStream_t stream) {
    const float* x       = (const float*)d_in[0];
    const int*   ei      = (const int*)d_in[1];
    const int*   batch   = (const int*)d_in[2];
    const float* gcn1_W  = (const float*)d_in[4];
    const float* gcn1_b  = (const float*)d_in[5];
    const float* gcn2_W  = (const float*)d_in[6];
    const float* gcn2_b  = (const float*)d_in[7];
    const float* gin0_w1 = (const float*)d_in[8];
    const float* gin0_b1 = (const float*)d_in[9];
    const float* gin0_w2 = (const float*)d_in[10];
    const float* gin0_b2 = (const float*)d_in[11];
    const float* gin_w1  = (const float*)d_in[12];
    const float* gin_b1  = (const float*)d_in[13];
    const float* gin_w2  = (const float*)d_in[14];
    const float* gin_b2  = (const float*)d_in[15];
    const float* bn_g    = (const float*)d_in[16];
    const float* bn_b    = (const float*)d_in[17];
    float* out = (float*)d_out;

    const int N = in_sizes[0] / FINC;   // 100000
    const int E = in_sizes[1] / 2;      // 400000
    const int G = out_size / REPW;      // 2500
    const int* srcv = ei;
    const int* dstv = ei + E;

    // Workspace (~261 MB, proven-passing footprint):
    // five fp32 [N][128] planes; packed-x split planes alias h1 (disjoint lifetimes).
    char* ws = (char*)d_ws;
    size_t off = 0;
    auto alloc = [&](size_t bytes) { char* p = ws + off; off += (bytes + 255) & ~(size_t)255; return p; };
    int*   cnt     = (int*)alloc((size_t)N * 4);
    int*   rowptr  = (int*)alloc(((size_t)N + 1) * 4);
    int*   cursor  = (int*)alloc((size_t)N * 4);
    int*   col     = (int*)alloc((size_t)E * 4);
    float* dis     = (float*)alloc((size_t)N * 4);
    float* bnsum   = (float*)alloc(768 * 4);
    float* coef    = (float*)alloc(768 * 4);
    float* cvec    = (float*)alloc(128 * 4);
    int*   start   = (int*)alloc(((size_t)G + 1) * 4);
    int*   tileSum = (int*)alloc(256 * 4);
    int*   tileOff = (int*)alloc(256 * 4);
    const size_t o96 = (size_t)128 * 96, o128 = (size_t)128 * 128;
    const size_t wtElems = 2 * o96 + 6 * o128;
    unsigned short* whi  = (unsigned short*)alloc(wtElems * 2);
    unsigned short* wlo  = (unsigned short*)alloc(wtElems * 2);
    unsigned short* fwhi = (unsigned short*)alloc(o128 * 2);
    unsigned short* fwlo = (unsigned short*)alloc(o128 * 2);
    const size_t fbytes = (size_t)N * DIMC * 4;
    float* bufT = (float*)alloc(fbytes);
    float* bufZ = (float*)alloc(fbytes);
    float* h0   = (float*)alloc(fbytes);
    float* h1   = (float*)alloc(fbytes);   // hosts packed x early (x dead before h1 written)
    float* h2   = (float*)alloc(fbytes);
    unsigned short* xhi = (unsigned short*)h1;                  // N*96*2 = 19.2 MB
    unsigned short* xlo = (unsigned short*)h1 + (size_t)N * 96; // +19.2 MB <= 51.2 MB
    (void)ws_size; (void)n_in;

    const size_t woff[8] = {0, o96, 2 * o96, 2 * o96 + o128, 2 * o96 + 2 * o128,
                            2 * o96 + 3 * o128, 2 * o96 + 4 * o128, 2 * o96 + 5 * o128};
    // order: gcn1, gin0_w1, gcn2, gin0_w2, gin_w1[0], gin_w1[1], gin_w2[0], gin_w2[1]

    const int T = 256;
    auto cdiv = [](long a, long b) { return (int)((a + b - 1) / b); };
    const int nStrips = cdiv(N, 32);      // 3125
    const int g96 = 768;                  // 3 blocks/CU (49 KB LDS)
    const int g128 = 512;                 // 2 blocks/CU (65 KB LDS)
    const int gatherGrid = cdiv((long)N * 32, T);
    const int nTiles = cdiv(N, SCAN_TILE);
    const float invN = 1.0f / (float)N;

    // ---- CSR build + norms + graph bounds + weight split + x pack ----
    k_fill_int<<<cdiv(N, T), T, 0, stream>>>(cnt, 0, N);
    k_count<<<cdiv(E, T), T, 0, stream>>>(dstv, cnt, E);
    k_tilesum<<<nTiles, T, 0, stream>>>(cnt, tileSum, N);
    k_tilescan<<<1, T, 0, stream>>>(tileSum, tileOff, rowptr, nTiles, N);
    k_tileemit<<<nTiles, T, 0, stream>>>(cnt, tileOff, rowptr, cursor, dis, N);
    k_scatter<<<cdiv(E, T), T, 0, stream>>>(srcv, dstv, cursor, col, E);
    k_bounds<<<cdiv(G + 1, T), T, 0, stream>>>(batch, start, N, G);
    k_fill<<<3, T, 0, stream>>>(bnsum, 0.f, 768);
    {
        dim3 g(64, 8);
        k_cvt_w<<<g, T, 0, stream>>>(gcn1_W, gin0_w1, gcn2_W, gin0_w2,
                                     gin_w1, gin_w1 + o128, gin_w2, gin_w2 + o128, whi, wlo);
    }
    k_pack_x<<<cdiv((long)N * 24, T), T, 0, stream>>>(x, xhi, xlo, N);

    // ---- GCN branch ----
    k_gemm_s<96, true, false><<<g96, T, 0, stream>>>(xhi, xlo, whi + woff[0], wlo + woff[0],
                                                     nullptr, dis, nullptr, bufT, N, 0, nStrips);
    k_gather_gcn<<<gatherGrid, T, 0, stream>>>((const float4*)bufT, rowptr, col, dis,
                                               (const float4*)gcn1_b, (float4*)bufZ, N);   // g1
    k_gemm_s<128, false, false><<<g128, T, 0, stream>>>(bufZ, nullptr, whi + woff[2], wlo + woff[2],
                                                        nullptr, dis, nullptr, bufT, N, 0, nStrips);
    k_gather_gcn<<<gatherGrid, T, 0, stream>>>((const float4*)bufT, rowptr, col, dis,
                                               (const float4*)gcn2_b, (float4*)h0, N);     // g2
    k_segmax_gcn<<<G, DIMC, 0, stream>>>(bufZ, h0, start, out);                            // groups 5..8

    // ---- GIN layer 0 ----
    k_gemm_s<96, true, false><<<g96, T, 0, stream>>>(xhi, xlo, whi + woff[1], wlo + woff[1],
                                                     nullptr, nullptr, nullptr, bufT, N, 0, nStrips);
    k_gather_gin<<<gatherGrid, T, 0, stream>>>((const float4*)bufT, rowptr, col,
                                               (const float4*)gin0_b1, (float4*)bufZ, N);
    k_gemm_s<128, false, true><<<g128, T, 0, stream>>>(bufZ, nullptr, whi + woff[3], wlo + woff[3],
                                                       gin0_b2, nullptr, bnsum, h0, N, 1, nStrips);
    k_bn_coef<<<1, DIMC, 0, stream>>>(bnsum, bn_g, bn_b, coef, invN);
    k_fold_w<<<DIMC, DIMC, 0, stream>>>(gin_w1, coef, fwhi, fwlo, cvec);

    // ---- GIN layer 1 (BN folded into weights; x planes in h1 are dead from here) ----
    k_gemm_s<128, false, false><<<g128, T, 0, stream>>>(h0, nullptr, fwhi, fwlo,
                                                        cvec, nullptr, nullptr, bufT, N, 0, nStrips);
    k_gather_gin<<<gatherGrid, T, 0, stream>>>((const float4*)bufT, rowptr, col,
                                               (const float4*)gin_b1, (float4*)bufZ, N);
    k_gemm_s<128, false, true><<<g128, T, 0, stream>>>(bufZ, nullptr, whi + woff[6], wlo + woff[6],
                                                       gin_b2, nullptr, bnsum + 256, h1, N, 1, nStrips);
    k_bn_coef<<<1, DIMC, 0, stream>>>(bnsum + 256, bn_g + DIMC, bn_b + DIMC, coef + 256, invN);
    k_fold_w<<<DIMC, DIMC, 0, stream>>>(gin_w1 + o128, coef + 256, fwhi, fwlo, cvec);

    // ---- GIN layer 2 ----
    k_gemm_s<128, false, false><<<g128, T, 0, stream>>>(h1, nullptr, fwhi, fwlo,
                                                        cvec, nullptr, nullptr, bufT, N, 0, nStrips);
    k_gather_gin<<<gatherGrid, T, 0, stream>>>((const float4*)bufT, rowptr, col,
                                               (const float4*)(gin_b1 + DIMC), (float4*)bufZ, N);
    k_gemm_s<128, false, true><<<g128, T, 0, stream>>>(bufZ, nullptr, whi + woff[7], wlo + woff[7],
                                                       gin_b2 + DIMC, nullptr, bnsum + 512, h2, N, 1, nStrips);
    k_bn_coef<<<1, DIMC, 0, stream>>>(bnsum + 512, bn_g + 2 * DIMC, bn_b + 2 * DIMC, coef + 512, invN);

    k_segmax_gin_all<<<G, DIMC, 0, stream>>>(h0, h1, h2, coef, start, out);                // groups 0..4
}

// Round 7
// 786.276 us; speedup vs baseline: 1.4307x; 1.4307x over previous
//
#include <hip/hip_runtime.h>
#include <math.h>

#define DIMC 128
#define FINC 78
#define REPW 1152        // 9 * 128
#define SCAN_TILE 1024   // elements per scan tile (256 threads x 4)

typedef __attribute__((ext_vector_type(8))) short short8x;
typedef __attribute__((ext_vector_type(4))) float f32x4;
typedef unsigned int u32;
typedef const __attribute__((address_space(1))) u32* gas_u32p;
typedef __attribute__((address_space(3))) u32* las_u32p;

__device__ inline float b2f(unsigned short u) {
    union { unsigned int i; float f; } v; v.i = ((unsigned int)u) << 16; return v.f;
}
__device__ inline unsigned short f2b(float f) {
    union { float f; unsigned int i; } v; v.f = f;
    unsigned int r = (v.i + 0x7FFFu + ((v.i >> 16) & 1u)) >> 16;
    return (unsigned short)r;
}

// 16B global -> LDS DMA (LDS dest = wave-uniform base + lane*16; our dest is linear in tid).
__device__ __forceinline__ void gld16(const void* g, void* l) {
    __builtin_amdgcn_global_load_lds((gas_u32p)g, (las_u32p)l, 16, 0, 0);
}

// ---------------- setup kernels ----------------

__global__ void k_fill_int(int* __restrict__ p, int v, int n) {
    int i = blockIdx.x * blockDim.x + threadIdx.x;
    if (i < n) p[i] = v;
}

__global__ void k_fill(float* __restrict__ p, float v, int n) {
    int i = blockIdx.x * blockDim.x + threadIdx.x;
    if (i < n) p[i] = v;
}

__global__ void k_count(const int* __restrict__ dst, int* __restrict__ cnt, int E) {
    int e = blockIdx.x * blockDim.x + threadIdx.x;
    if (e < E) atomicAdd(&cnt[dst[e]], 1);
}

__launch_bounds__(256)
__global__ void k_tilesum(const int* __restrict__ cnt, int* __restrict__ tileSum, int N) {
    __shared__ int red[256];
    int base = blockIdx.x * SCAN_TILE;
    int s = 0;
    for (int i = threadIdx.x; i < SCAN_TILE; i += 256) {
        int idx = base + i;
        if (idx < N) s += cnt[idx];
    }
    red[threadIdx.x] = s;
    __syncthreads();
    for (int d = 128; d > 0; d >>= 1) {
        if (threadIdx.x < d) red[threadIdx.x] += red[threadIdx.x + d];
        __syncthreads();
    }
    if (threadIdx.x == 0) tileSum[blockIdx.x] = red[0];
}

__launch_bounds__(256)
__global__ void k_tilescan(const int* __restrict__ tileSum, int* __restrict__ tileOff,
                           int* __restrict__ rowptr, int T, int N) {
    __shared__ int sh[256];
    int t = threadIdx.x;
    int orig = (t < T) ? tileSum[t] : 0;
    sh[t] = orig;
    __syncthreads();
    for (int d = 1; d < 256; d <<= 1) {
        int v = (t >= d) ? sh[t - d] : 0;
        __syncthreads();
        sh[t] += v;
        __syncthreads();
    }
    if (t < T) tileOff[t] = sh[t] - orig;
    if (t == 255) rowptr[N] = sh[255];
}

__launch_bounds__(256)
__global__ void k_tileemit(const int* __restrict__ cnt, const int* __restrict__ tileOff,
                           int* __restrict__ rowptr, int* __restrict__ cursor,
                           float* __restrict__ dis, int N) {
    __shared__ int sh[256];
    int t = threadIdx.x;
    int base = blockIdx.x * SCAN_TILE;
    int idx0 = base + t * 4;
    int v0 = 0, v1 = 0, v2 = 0, v3 = 0;
    if (idx0 + 3 < N) {
        int4 v = *(const int4*)(cnt + idx0);
        v0 = v.x; v1 = v.y; v2 = v.z; v3 = v.w;
    } else {
        if (idx0 + 0 < N) v0 = cnt[idx0 + 0];
        if (idx0 + 1 < N) v1 = cnt[idx0 + 1];
        if (idx0 + 2 < N) v2 = cnt[idx0 + 2];
        if (idx0 + 3 < N) v3 = cnt[idx0 + 3];
    }
    int s0 = v0, s1 = s0 + v1, s2 = s1 + v2, s3 = s2 + v3;
    sh[t] = s3;
    __syncthreads();
    for (int d = 1; d < 256; d <<= 1) {
        int v = (t >= d) ? sh[t - d] : 0;
        __syncthreads();
        sh[t] += v;
        __syncthreads();
    }
    int gbase = tileOff[blockIdx.x] + ((t == 0) ? 0 : sh[t - 1]);
    int ex[4] = {0, s0, s1, s2};
    int vv[4] = {v0, v1, v2, v3};
#pragma unroll
    for (int j = 0; j < 4; ++j) {
        int idx = idx0 + j;
        if (idx < N) {
            int r = gbase + ex[j];
            rowptr[idx] = r;
            cursor[idx] = r;
            dis[idx] = rsqrtf((float)vv[j] + 1.0f);
        }
    }
}

__global__ void k_scatter(const int* __restrict__ src, const int* __restrict__ dst,
                          int* __restrict__ cursor, int* __restrict__ col, int E) {
    int e = blockIdx.x * blockDim.x + threadIdx.x;
    if (e < E) {
        int pos = atomicAdd(&cursor[dst[e]], 1);
        col[pos] = src[e];
    }
}

__global__ void k_bounds(const int* __restrict__ batch, int* __restrict__ start, int N, int G) {
    int g = blockIdx.x * blockDim.x + threadIdx.x;
    if (g <= G) {
        int lo = 0, hi = N;
        while (lo < hi) { int mid = (lo + hi) >> 1; if (batch[mid] < g) lo = mid + 1; else hi = mid; }
        start[g] = lo;
    }
}

// ---------------- weight split: fp32 W[k][n] -> transposed bf16 hi/lo [n][k] ----------------

__global__ void k_cvt_w(const float* __restrict__ s0, const float* __restrict__ s1,
                        const float* __restrict__ s2, const float* __restrict__ s3,
                        const float* __restrict__ s4, const float* __restrict__ s5,
                        const float* __restrict__ s6, const float* __restrict__ s7,
                        unsigned short* __restrict__ whi, unsigned short* __restrict__ wlo) {
    int my = blockIdx.y;
    const float* src; int Ksrc, KP; size_t dstoff;
    const size_t o96 = (size_t)128 * 96, o128 = (size_t)128 * 128;
    switch (my) {
        case 0: src = s0; Ksrc = 78;  KP = 96;  dstoff = 0; break;
        case 1: src = s1; Ksrc = 78;  KP = 96;  dstoff = o96; break;
        case 2: src = s2; Ksrc = 128; KP = 128; dstoff = 2 * o96; break;
        case 3: src = s3; Ksrc = 128; KP = 128; dstoff = 2 * o96 + o128; break;
        case 4: src = s4; Ksrc = 128; KP = 128; dstoff = 2 * o96 + 2 * o128; break;
        case 5: src = s5; Ksrc = 128; KP = 128; dstoff = 2 * o96 + 3 * o128; break;
        case 6: src = s6; Ksrc = 128; KP = 128; dstoff = 2 * o96 + 4 * o128; break;
        default: src = s7; Ksrc = 128; KP = 128; dstoff = 2 * o96 + 5 * o128; break;
    }
    int i = blockIdx.x * blockDim.x + threadIdx.x;
    if (i < 128 * KP) {
        int n = i / KP, k = i - n * KP;
        float v = (k < Ksrc) ? src[(size_t)k * DIMC + n] : 0.f;
        unsigned short hi = f2b(v);
        unsigned short lo = f2b(v - b2f(hi));
        whi[dstoff + i] = hi;
        wlo[dstoff + i] = lo;
    }
}

// ---------------- pad x: fp32 [N][78] -> fp32 [N][96] (zero-padded cols) ----------------

__global__ void k_pad_x(const float* __restrict__ x, float* __restrict__ x96, int N) {
    int i = blockIdx.x * blockDim.x + threadIdx.x;
    int r = i / 24, c4 = (i - r * 24) * 4;
    if (r >= N) return;
    float v[4];
#pragma unroll
    for (int j = 0; j < 4; ++j) { int k = c4 + j; v[j] = (k < FINC) ? x[(size_t)r * FINC + k] : 0.f; }
    *(float4*)(x96 + (size_t)r * 96 + c4) = make_float4(v[0], v[1], v[2], v[3]);
}

// ---------------- MFMA GEMM: fp32 A (DMA-staged), split-bf16 B (DMA-staged), fp32 C ----------------
// 128-row block, 4 waves; wave w owns rows [row0 + w*32, +32) x all 128 cols
// (each A value converted to bf16 hi/lo by exactly one lane).
// A: raw fp32 chunk (128 rows x 32 k = 16 KB) DMA'd with 8-unit source-XOR:
//    LDS slot (U, R) holds source unit U^(R&7) of row R (unit = 4 floats).
// B: whi/wlo [128 n][KP k] chunk (16 KB) DMA'd with the round-4-proven 4-unit XOR.
// Double-buffered, counted vmcnt(8) (8 DMA ops per chunk), raw barriers.
// MFMA (HW-verified r4/r5): acc = mfma(b_frag, a_frag) -> C[row=lm-based][col=ct*16+q*4+i].

template<int KP, bool STATS>
__launch_bounds__(256, 2)
__global__ void k_gemm_dma(const float* __restrict__ A,
                           const unsigned short* __restrict__ Bhi,
                           const unsigned short* __restrict__ Blo,
                           const float* __restrict__ bias, const float* __restrict__ rowScale,
                           float* __restrict__ statsOut, float* __restrict__ C,
                           int N, int doRelu) {
    constexpr int NT = KP / 32;
    __shared__ float ldsA[2][4096];                // 2 x 16 KB (1024 units x 4 floats)
    __shared__ unsigned short ldsB[2][2][4096];    // 2 x 16 KB (hi, lo)
    __shared__ float sStats[256];
    const int tid = threadIdx.x;
    const int wave = tid >> 6, lane = tid & 63;
    const int lm = lane & 15, q = lane >> 4;
    const int row0 = blockIdx.x * 128;
    const int mrow = wave * 32;

    // staging addressing
    const int rr = tid & 127;
    const int g0 = tid >> 7;
    const int bo0 = ((g0 ^ (rr & 3)) << 3);        // B source octet offsets (shorts)
    const int bo1 = (((2 + g0) ^ (rr & 3)) << 3);
    const size_t brow = (size_t)rr * KP;
    const int bu0 = tid << 3;                      // B LDS offsets (shorts)
    const int bu1 = (256 + tid) << 3;
    const size_t arow = (size_t)(row0 + rr) * KP;  // fp32 row (floats)
    int asrc[4];
#pragma unroll
    for (int o = 0; o < 4; ++o) asrc[o] = (((2 * o + g0) ^ (rr & 7)) << 2);  // floats

    auto stage = [&](int c, int d) {
        const int cb = c << 5;                     // chunk base (floats == shorts count x2? no: floats for A, shorts for B: both 32/chunk-coordinate)
#pragma unroll
        for (int o = 0; o < 4; ++o)
            gld16(A + arow + cb + asrc[o], &ldsA[d][(o * 256 + tid) << 2]);
        gld16(Bhi + brow + cb + bo0, &ldsB[d][0][bu0]);
        gld16(Bhi + brow + cb + bo1, &ldsB[d][0][bu1]);
        gld16(Blo + brow + cb + bo0, &ldsB[d][1][bu0]);
        gld16(Blo + brow + cb + bo1, &ldsB[d][1][bu1]);
    };

    f32x4 acc[2][8];
#pragma unroll
    for (int a = 0; a < 2; ++a)
#pragma unroll
        for (int b = 0; b < 8; ++b) acc[a][b] = (f32x4){0.f, 0.f, 0.f, 0.f};

    stage(0, 0);
#pragma unroll
    for (int t = 0; t < NT; ++t) {
        const int cur = t & 1;
        if (t + 1 < NT) {
            stage(t + 1, cur ^ 1);
            asm volatile("s_waitcnt vmcnt(8)" ::: "memory");   // chunk t's 8 ops landed
        } else {
            asm volatile("s_waitcnt vmcnt(0)" ::: "memory");
        }
        __builtin_amdgcn_s_barrier();
        __builtin_amdgcn_sched_barrier(0);

        // A frags: wave's rows, fp32 -> bf16 hi/lo in-register
        short8x ah[2], al[2];
#pragma unroll
        for (int rt = 0; rt < 2; ++rt) {
            int m = mrow + rt * 16 + lm;
            int s0 = (2 * q) ^ (m & 7), s1 = (2 * q + 1) ^ (m & 7);
            float4 f0 = *(const float4*)&ldsA[cur][(s0 * 128 + m) << 2];
            float4 f1 = *(const float4*)&ldsA[cur][(s1 * 128 + m) << 2];
            float ff[8] = {f0.x, f0.y, f0.z, f0.w, f1.x, f1.y, f1.z, f1.w};
#pragma unroll
            for (int j = 0; j < 8; ++j) {
                unsigned short h = f2b(ff[j]);
                ah[rt][j] = (short)h;
                al[rt][j] = (short)f2b(ff[j] - b2f(h));
            }
        }
#pragma unroll
        for (int ct = 0; ct < 8; ++ct) {
            int n = ct * 16 + lm;
            int sl = ((q ^ (n & 3)) * 128 + n) << 3;
            short8x bh = *(const short8x*)&ldsB[cur][0][sl];
            short8x bl = *(const short8x*)&ldsB[cur][1][sl];
#pragma unroll
            for (int rt = 0; rt < 2; ++rt) {
                acc[rt][ct] = __builtin_amdgcn_mfma_f32_16x16x32_bf16(bh, ah[rt], acc[rt][ct], 0, 0, 0);
                acc[rt][ct] = __builtin_amdgcn_mfma_f32_16x16x32_bf16(bh, al[rt], acc[rt][ct], 0, 0, 0);
                acc[rt][ct] = __builtin_amdgcn_mfma_f32_16x16x32_bf16(bl, ah[rt], acc[rt][ct], 0, 0, 0);
            }
        }
        __builtin_amdgcn_s_barrier();   // protect LDS bufs about to be overwritten
    }

    // epilogue: bias -> relu -> rowScale, fp32 float4 stores, optional column stats
    float cs[8][4], cq[8][4];
    if constexpr (STATS) {
#pragma unroll
        for (int a = 0; a < 8; ++a)
#pragma unroll
            for (int b = 0; b < 4; ++b) { cs[a][b] = 0.f; cq[a][b] = 0.f; }
    }

#pragma unroll
    for (int rt = 0; rt < 2; ++rt) {
        int grow = row0 + mrow + rt * 16 + lm;
        if (grow < N) {
            float sc = rowScale ? rowScale[grow] : 1.f;
#pragma unroll
            for (int ct = 0; ct < 8; ++ct) {
                float vv[4];
#pragma unroll
                for (int i = 0; i < 4; ++i) {
                    float v = acc[rt][ct][i];
                    if (bias) v += bias[ct * 16 + q * 4 + i];
                    if (doRelu) v = fmaxf(v, 0.f);
                    v *= sc;
                    vv[i] = v;
                    if constexpr (STATS) { cs[ct][i] += v; cq[ct][i] = fmaf(v, v, cq[ct][i]); }
                }
                *(float4*)(C + (size_t)grow * DIMC + ct * 16 + q * 4) =
                    make_float4(vv[0], vv[1], vv[2], vv[3]);
            }
        }
    }

    if constexpr (STATS) {
        sStats[tid] = 0.f;
        __syncthreads();
#pragma unroll
        for (int ct = 0; ct < 8; ++ct)
#pragma unroll
            for (int i = 0; i < 4; ++i) {
                float vs = cs[ct][i], vq = cq[ct][i];
#pragma unroll
                for (int o = 1; o < 16; o <<= 1) { vs += __shfl_xor(vs, o); vq += __shfl_xor(vq, o); }
                if (lm == 0) {
                    int colg = ct * 16 + q * 4 + i;
                    atomicAdd(&sStats[colg], vs);
                    atomicAdd(&sStats[DIMC + colg], vq);
                }
            }
        __syncthreads();
        atomicAdd(&statsOut[tid], sStats[tid]);
    }
}

// ---------------- BN coefficients: sums -> (scale, shift) ----------------

__global__ void k_bn_coef(const float* __restrict__ bnsum, const float* __restrict__ gamma,
                          const float* __restrict__ beta, float* __restrict__ coef, float invN) {
    int c = threadIdx.x;  // 128
    float mu  = bnsum[c] * invN;
    float var = bnsum[128 + c] * invN - mu * mu;
    float inv = rsqrtf(var + 1e-5f);
    float s = gamma[c] * inv;
    coef[c] = s;
    coef[128 + c] = beta[c] - mu * s;
}

// ---- fold BN affine into next layer's W1: W'[n][k] = s[k]*w1[k][n], cvec[n] = sum_k t[k]*w1[k][n]

__global__ void k_fold_w(const float* __restrict__ w1, const float* __restrict__ coefL,
                         unsigned short* __restrict__ fwhi, unsigned short* __restrict__ fwlo,
                         float* __restrict__ cvec) {
    __shared__ float red[128];
    int n = blockIdx.x, k = threadIdx.x;
    float w = w1[(size_t)k * DIMC + n];
    float ws = w * coefL[k];
    unsigned short h = f2b(ws);
    fwhi[(size_t)n * DIMC + k] = h;
    fwlo[(size_t)n * DIMC + k] = f2b(ws - b2f(h));
    red[k] = w * coefL[DIMC + k];
    __syncthreads();
    for (int d = 64; d > 0; d >>= 1) { if (k < d) red[k] += red[k + d]; __syncthreads(); }
    if (k == 0) cvec[n] = red[0];
}

// ---------------- CSR gather aggregation (fp32, round-0 proven) ----------------

__global__ void k_gather_gcn(const float4* __restrict__ t, const int* __restrict__ rowptr,
                             const int* __restrict__ col, const float* __restrict__ dis,
                             const float4* __restrict__ bias, float4* __restrict__ out, int N) {
    int i = blockIdx.x * blockDim.x + threadIdx.x;
    int node = i >> 5, c4 = i & 31;
    if (node >= N) return;
    int s = rowptr[node], e = rowptr[node + 1];
    float4 acc = t[(size_t)node * 32 + c4];
    for (int k = s; k < e; ++k) {
        float4 v = t[(size_t)col[k] * 32 + c4];
        acc.x += v.x; acc.y += v.y; acc.z += v.z; acc.w += v.w;
    }
    float d = dis[node];
    float4 b = bias[c4];
    float4 o;
    o.x = fmaxf(acc.x * d + b.x, 0.f);
    o.y = fmaxf(acc.y * d + b.y, 0.f);
    o.z = fmaxf(acc.z * d + b.z, 0.f);
    o.w = fmaxf(acc.w * d + b.w, 0.f);
    out[(size_t)node * 32 + c4] = o;
}

__global__ void k_gather_gin(const float4* __restrict__ t, const int* __restrict__ rowptr,
                             const int* __restrict__ col, const float4* __restrict__ bias,
                             float4* __restrict__ out, int N) {
    int i = blockIdx.x * blockDim.x + threadIdx.x;
    int node = i >> 5, c4 = i & 31;
    if (node >= N) return;
    int s = rowptr[node], e = rowptr[node + 1];
    float4 acc = t[(size_t)node * 32 + c4];
    for (int k = s; k < e; ++k) {
        float4 v = t[(size_t)col[k] * 32 + c4];
        acc.x += v.x; acc.y += v.y; acc.z += v.z; acc.w += v.w;
    }
    float4 b = bias[c4];
    float4 o;
    o.x = fmaxf(acc.x + b.x, 0.f);
    o.y = fmaxf(acc.y + b.y, 0.f);
    o.z = fmaxf(acc.z + b.z, 0.f);
    o.w = fmaxf(acc.w + b.w, 0.f);
    out[(size_t)node * 32 + c4] = o;
}

// ---------------- segment max (fp32, round-0 proven) ----------------

__global__ void k_segmax_gin_all(const float* __restrict__ h0, const float* __restrict__ h1,
                                 const float* __restrict__ h2, const float* __restrict__ coef,
                                 const int* __restrict__ start, float* __restrict__ out) {
    int g = blockIdx.x, c = threadIdx.x;
    float s0 = coef[c],       t0 = coef[128 + c];
    float s1 = coef[256 + c], t1 = coef[384 + c];
    float s2 = coef[512 + c], t2 = coef[640 + c];
    int s = start[g], e = start[g + 1];
    float m0 = -INFINITY, m1 = -INFINITY, m2 = -INFINITY, mm = -INFINITY, me = -INFINITY;
    for (int n = s; n < e; ++n) {
        size_t idx = (size_t)n * DIMC + c;
        float a0 = fmaf(h0[idx], s0, t0);
        float a1 = fmaf(h1[idx], s1, t1);
        float a2 = fmaf(h2[idx], s2, t2);
        m0 = fmaxf(m0, a0); m1 = fmaxf(m1, a1); m2 = fmaxf(m2, a2);
        mm = fmaxf(mm, a0 * a1 * a2);
        me = fmaxf(me, a0 + a1 + a2);
    }
    size_t o = (size_t)g * REPW + c;
    out[o]            = m0;
    out[o + 1 * DIMC] = m1;
    out[o + 2 * DIMC] = m2;
    out[o + 3 * DIMC] = mm;
    out[o + 4 * DIMC] = me;
}

__global__ void k_segmax_gcn(const float* __restrict__ G1, const float* __restrict__ G2,
                             const int* __restrict__ start, float* __restrict__ out) {
    int g = blockIdx.x, c = threadIdx.x;
    int s = start[g], e = start[g + 1];
    float m1 = -INFINITY, m2 = -INFINITY, ma = -INFINITY, mm = -INFINITY;
    for (int n = s; n < e; ++n) {
        float a = G1[(size_t)n * DIMC + c], b = G2[(size_t)n * DIMC + c];
        m1 = fmaxf(m1, a); m2 = fmaxf(m2, b);
        ma = fmaxf(ma, a + b); mm = fmaxf(mm, a * b);
    }
    size_t o = (size_t)g * REPW + c;
    out[o + 5 * DIMC] = m1;
    out[o + 6 * DIMC] = m2;
    out[o + 7 * DIMC] = ma;
    out[o + 8 * DIMC] = mm;
}

// ---------------- launch ----------------

extern "C" void kernel_launch(void* const* d_in, const int* in_sizes, int n_in,
                              void* d_out, int out_size, void* d_ws, size_t ws_size,
                              hipStream_t stream) {
    const float* x       = (const float*)d_in[0];
    const int*   ei      = (const int*)d_in[1];
    const int*   batch   = (const int*)d_in[2];
    const float* gcn1_W  = (const float*)d_in[4];
    const float* gcn1_b  = (const float*)d_in[5];
    const float* gcn2_W  = (const float*)d_in[6];
    const float* gcn2_b  = (const float*)d_in[7];
    const float* gin0_w1 = (const float*)d_in[8];
    const float* gin0_b1 = (const float*)d_in[9];
    const float* gin0_w2 = (const float*)d_in[10];
    const float* gin0_b2 = (const float*)d_in[11];
    const float* gin_w1  = (const float*)d_in[12];
    const float* gin_b1  = (const float*)d_in[13];
    const float* gin_w2  = (const float*)d_in[14];
    const float* gin_b2  = (const float*)d_in[15];
    const float* bn_g    = (const float*)d_in[16];
    const float* bn_b    = (const float*)d_in[17];
    float* out = (float*)d_out;

    const int N = in_sizes[0] / FINC;   // 100000
    const int E = in_sizes[1] / 2;      // 400000
    const int G = out_size / REPW;      // 2500
    const int* srcv = ei;
    const int* dstv = ei + E;

    // Workspace (~261 MB, proven-safe footprint). x96 (fp32 padded x, 38.4 MB)
    // aliases h1 (disjoint lifetimes: x dead before h1 first written).
    // GEMM A-input DMA may read up to 96 rows past N; all A-input buffers
    // (x96-in-h1, bufZ, h0, h1) are followed by other ws allocations -> in-bounds.
    char* ws = (char*)d_ws;
    size_t off = 0;
    auto alloc = [&](size_t bytes) { char* p = ws + off; off += (bytes + 255) & ~(size_t)255; return p; };
    int*   cnt     = (int*)alloc((size_t)N * 4);
    int*   rowptr  = (int*)alloc(((size_t)N + 1) * 4);
    int*   cursor  = (int*)alloc((size_t)N * 4);
    int*   col     = (int*)alloc((size_t)E * 4);
    float* dis     = (float*)alloc((size_t)N * 4);
    float* bnsum   = (float*)alloc(768 * 4);
    float* coef    = (float*)alloc(768 * 4);
    float* cvec    = (float*)alloc(128 * 4);
    int*   start   = (int*)alloc(((size_t)G + 1) * 4);
    int*   tileSum = (int*)alloc(256 * 4);
    int*   tileOff = (int*)alloc(256 * 4);
    const size_t o96 = (size_t)128 * 96, o128 = (size_t)128 * 128;
    const size_t wtElems = 2 * o96 + 6 * o128;
    unsigned short* whi  = (unsigned short*)alloc(wtElems * 2);
    unsigned short* wlo  = (unsigned short*)alloc(wtElems * 2);
    unsigned short* fwhi = (unsigned short*)alloc(o128 * 2);
    unsigned short* fwlo = (unsigned short*)alloc(o128 * 2);
    const size_t fbytes = (size_t)N * DIMC * 4;
    float* bufT = (float*)alloc(fbytes);
    float* bufZ = (float*)alloc(fbytes);
    float* h0   = (float*)alloc(fbytes);
    float* h1   = (float*)alloc(fbytes);   // hosts x96 early
    float* h2   = (float*)alloc(fbytes);
    float* x96  = h1;                      // N*96*4 = 38.4 MB (+DMA overrun) <= 51.2 MB
    (void)ws_size; (void)n_in;

    const size_t woff[8] = {0, o96, 2 * o96, 2 * o96 + o128, 2 * o96 + 2 * o128,
                            2 * o96 + 3 * o128, 2 * o96 + 4 * o128, 2 * o96 + 5 * o128};
    // order: gcn1, gin0_w1, gcn2, gin0_w2, gin_w1[0], gin_w1[1], gin_w2[0], gin_w2[1]

    const int T = 256;
    auto cdiv = [](long a, long b) { return (int)((a + b - 1) / b); };
    const int gemmGrid = cdiv(N, 128);
    const int gatherGrid = cdiv((long)N * 32, T);
    const int nTiles = cdiv(N, SCAN_TILE);
    const float invN = 1.0f / (float)N;

    // ---- CSR build + norms + graph bounds + weight split + x pad ----
    k_fill_int<<<cdiv(N, T), T, 0, stream>>>(cnt, 0, N);
    k_count<<<cdiv(E, T), T, 0, stream>>>(dstv, cnt, E);
    k_tilesum<<<nTiles, T, 0, stream>>>(cnt, tileSum, N);
    k_tilescan<<<1, T, 0, stream>>>(tileSum, tileOff, rowptr, nTiles, N);
    k_tileemit<<<nTiles, T, 0, stream>>>(cnt, tileOff, rowptr, cursor, dis, N);
    k_scatter<<<cdiv(E, T), T, 0, stream>>>(srcv, dstv, cursor, col, E);
    k_bounds<<<cdiv(G + 1, T), T, 0, stream>>>(batch, start, N, G);
    k_fill<<<3, T, 0, stream>>>(bnsum, 0.f, 768);
    {
        dim3 g(64, 8);
        k_cvt_w<<<g, T, 0, stream>>>(gcn1_W, gin0_w1, gcn2_W, gin0_w2,
                                     gin_w1, gin_w1 + o128, gin_w2, gin_w2 + o128, whi, wlo);
    }
    k_pad_x<<<cdiv((long)N * 24, T), T, 0, stream>>>(x, x96, N);

    // ---- GCN branch ----
    k_gemm_dma<96, false><<<gemmGrid, T, 0, stream>>>(x96, whi + woff[0], wlo + woff[0],
                                                      nullptr, dis, nullptr, bufT, N, 0);
    k_gather_gcn<<<gatherGrid, T, 0, stream>>>((const float4*)bufT, rowptr, col, dis,
                                               (const float4*)gcn1_b, (float4*)bufZ, N);   // g1
    k_gemm_dma<128, false><<<gemmGrid, T, 0, stream>>>(bufZ, whi + woff[2], wlo + woff[2],
                                                       nullptr, dis, nullptr, bufT, N, 0);
    k_gather_gcn<<<gatherGrid, T, 0, stream>>>((const float4*)bufT, rowptr, col, dis,
                                               (const float4*)gcn2_b, (float4*)h0, N);     // g2
    k_segmax_gcn<<<G, DIMC, 0, stream>>>(bufZ, h0, start, out);                            // groups 5..8

    // ---- GIN layer 0 ----
    k_gemm_dma<96, false><<<gemmGrid, T, 0, stream>>>(x96, whi + woff[1], wlo + woff[1],
                                                      nullptr, nullptr, nullptr, bufT, N, 0);
    k_gather_gin<<<gatherGrid, T, 0, stream>>>((const float4*)bufT, rowptr, col,
                                               (const float4*)gin0_b1, (float4*)bufZ, N);
    k_gemm_dma<128, true><<<gemmGrid, T, 0, stream>>>(bufZ, whi + woff[3], wlo + woff[3],
                                                      gin0_b2, nullptr, bnsum, h0, N, 1);
    k_bn_coef<<<1, DIMC, 0, stream>>>(bnsum, bn_g, bn_b, coef, invN);
    k_fold_w<<<DIMC, DIMC, 0, stream>>>(gin_w1, coef, fwhi, fwlo, cvec);

    // ---- GIN layer 1 (BN folded into weights; x96 in h1 dead from here) ----
    k_gemm_dma<128, false><<<gemmGrid, T, 0, stream>>>(h0, fwhi, fwlo,
                                                       cvec, nullptr, nullptr, bufT, N, 0);
    k_gather_gin<<<gatherGrid, T, 0, stream>>>((const float4*)bufT, rowptr, col,
                                               (const float4*)gin_b1, (float4*)bufZ, N);
    k_gemm_dma<128, true><<<gemmGrid, T, 0, stream>>>(bufZ, whi + woff[6], wlo + woff[6],
                                                      gin_b2, nullptr, bnsum + 256, h1, N, 1);
    k_bn_coef<<<1, DIMC, 0, stream>>>(bnsum + 256, bn_g + DIMC, bn_b + DIMC, coef + 256, invN);
    k_fold_w<<<DIMC, DIMC, 0, stream>>>(gin_w1 + o128, coef + 256, fwhi, fwlo, cvec);

    // ---- GIN layer 2 ----
    k_gemm_dma<128, false><<<gemmGrid, T, 0, stream>>>(h1, fwhi, fwlo,
                                                       cvec, nullptr, nullptr, bufT, N, 0);
    k_gather_gin<<<gatherGrid, T, 0, stream>>>((const float4*)bufT, rowptr, col,
                                               (const float4*)(gin_b1 + DIMC), (float4*)bufZ, N);
    k_gemm_dma<128, true><<<gemmGrid, T, 0, stream>>>(bufZ, whi + woff[7], wlo + woff[7],
                                                      gin_b2 + DIMC, nullptr, bnsum + 512, h2, N, 1);
    k_bn_coef<<<1, DIMC, 0, stream>>>(bnsum + 512, bn_g + 2 * DIMC, bn_b + 2 * DIMC, coef + 512, invN);

    k_segmax_gin_all<<<G, DIMC, 0, stream>>>(h0, h1, h2, coef, start, out);                // groups 0..4
}

// Round 8
// 759.595 us; speedup vs baseline: 1.4810x; 1.0351x over previous
//
#include <hip/hip_runtime.h>
#include <math.h>

#define DIMC 128
#define FINC 78
#define REPW 1152        // 9 * 128
#define SCAN_TILE 1024   // elements per scan tile (256 threads x 4)

typedef __attribute__((ext_vector_type(8))) short short8x;
typedef __attribute__((ext_vector_type(4))) float f32x4;
typedef unsigned int u32;
typedef const __attribute__((address_space(1))) u32* gas_u32p;
typedef __attribute__((address_space(3))) u32* las_u32p;

__device__ inline float b2f(unsigned short u) {
    union { unsigned int i; float f; } v; v.i = ((unsigned int)u) << 16; return v.f;
}
__device__ inline unsigned short f2b(float f) {
    union { float f; unsigned int i; } v; v.f = f;
    unsigned int r = (v.i + 0x7FFFu + ((v.i >> 16) & 1u)) >> 16;
    return (unsigned short)r;
}

// 16B global -> LDS DMA (LDS dest = wave-uniform base + lane*16; our dest is linear in tid).
__device__ __forceinline__ void gld16(const void* g, void* l) {
    __builtin_amdgcn_global_load_lds((gas_u32p)g, (las_u32p)l, 16, 0, 0);
}

// ---------------- setup kernels ----------------

__global__ void k_fill_int(int* __restrict__ p, int v, int n) {
    int i = blockIdx.x * blockDim.x + threadIdx.x;
    if (i < n) p[i] = v;
}

__global__ void k_fill(float* __restrict__ p, float v, int n) {
    int i = blockIdx.x * blockDim.x + threadIdx.x;
    if (i < n) p[i] = v;
}

__global__ void k_count(const int* __restrict__ dst, int* __restrict__ cnt, int E) {
    int e = blockIdx.x * blockDim.x + threadIdx.x;
    if (e < E) atomicAdd(&cnt[dst[e]], 1);
}

__launch_bounds__(256)
__global__ void k_tilesum(const int* __restrict__ cnt, int* __restrict__ tileSum, int N) {
    __shared__ int red[256];
    int base = blockIdx.x * SCAN_TILE;
    int s = 0;
    for (int i = threadIdx.x; i < SCAN_TILE; i += 256) {
        int idx = base + i;
        if (idx < N) s += cnt[idx];
    }
    red[threadIdx.x] = s;
    __syncthreads();
    for (int d = 128; d > 0; d >>= 1) {
        if (threadIdx.x < d) red[threadIdx.x] += red[threadIdx.x + d];
        __syncthreads();
    }
    if (threadIdx.x == 0) tileSum[blockIdx.x] = red[0];
}

__launch_bounds__(256)
__global__ void k_tilescan(const int* __restrict__ tileSum, int* __restrict__ tileOff,
                           int* __restrict__ rowptr, int T, int N) {
    __shared__ int sh[256];
    int t = threadIdx.x;
    int orig = (t < T) ? tileSum[t] : 0;
    sh[t] = orig;
    __syncthreads();
    for (int d = 1; d < 256; d <<= 1) {
        int v = (t >= d) ? sh[t - d] : 0;
        __syncthreads();
        sh[t] += v;
        __syncthreads();
    }
    if (t < T) tileOff[t] = sh[t] - orig;
    if (t == 255) rowptr[N] = sh[255];
}

__launch_bounds__(256)
__global__ void k_tileemit(const int* __restrict__ cnt, const int* __restrict__ tileOff,
                           int* __restrict__ rowptr, int* __restrict__ cursor,
                           float* __restrict__ dis, int N) {
    __shared__ int sh[256];
    int t = threadIdx.x;
    int base = blockIdx.x * SCAN_TILE;
    int idx0 = base + t * 4;
    int v0 = 0, v1 = 0, v2 = 0, v3 = 0;
    if (idx0 + 3 < N) {
        int4 v = *(const int4*)(cnt + idx0);
        v0 = v.x; v1 = v.y; v2 = v.z; v3 = v.w;
    } else {
        if (idx0 + 0 < N) v0 = cnt[idx0 + 0];
        if (idx0 + 1 < N) v1 = cnt[idx0 + 1];
        if (idx0 + 2 < N) v2 = cnt[idx0 + 2];
        if (idx0 + 3 < N) v3 = cnt[idx0 + 3];
    }
    int s0 = v0, s1 = s0 + v1, s2 = s1 + v2, s3 = s2 + v3;
    sh[t] = s3;
    __syncthreads();
    for (int d = 1; d < 256; d <<= 1) {
        int v = (t >= d) ? sh[t - d] : 0;
        __syncthreads();
        sh[t] += v;
        __syncthreads();
    }
    int gbase = tileOff[blockIdx.x] + ((t == 0) ? 0 : sh[t - 1]);
    int ex[4] = {0, s0, s1, s2};
    int vv[4] = {v0, v1, v2, v3};
#pragma unroll
    for (int j = 0; j < 4; ++j) {
        int idx = idx0 + j;
        if (idx < N) {
            int r = gbase + ex[j];
            rowptr[idx] = r;
            cursor[idx] = r;
            dis[idx] = rsqrtf((float)vv[j] + 1.0f);
        }
    }
}

__global__ void k_scatter(const int* __restrict__ src, const int* __restrict__ dst,
                          int* __restrict__ cursor, int* __restrict__ col, int E) {
    int e = blockIdx.x * blockDim.x + threadIdx.x;
    if (e < E) {
        int pos = atomicAdd(&cursor[dst[e]], 1);
        col[pos] = src[e];
    }
}

__global__ void k_bounds(const int* __restrict__ batch, int* __restrict__ start, int N, int G) {
    int g = blockIdx.x * blockDim.x + threadIdx.x;
    if (g <= G) {
        int lo = 0, hi = N;
        while (lo < hi) { int mid = (lo + hi) >> 1; if (batch[mid] < g) lo = mid + 1; else hi = mid; }
        start[g] = lo;
    }
}

// ---------------- weight split: fp32 W[k][n] -> transposed bf16 hi/lo [n][k] ----------------

__global__ void k_cvt_w(const float* __restrict__ s0, const float* __restrict__ s1,
                        const float* __restrict__ s2, const float* __restrict__ s3,
                        const float* __restrict__ s4, const float* __restrict__ s5,
                        const float* __restrict__ s6, const float* __restrict__ s7,
                        unsigned short* __restrict__ whi, unsigned short* __restrict__ wlo) {
    int my = blockIdx.y;
    const float* src; int Ksrc, KP; size_t dstoff;
    const size_t o96 = (size_t)128 * 96, o128 = (size_t)128 * 128;
    switch (my) {
        case 0: src = s0; Ksrc = 78;  KP = 96;  dstoff = 0; break;
        case 1: src = s1; Ksrc = 78;  KP = 96;  dstoff = o96; break;
        case 2: src = s2; Ksrc = 128; KP = 128; dstoff = 2 * o96; break;
        case 3: src = s3; Ksrc = 128; KP = 128; dstoff = 2 * o96 + o128; break;
        case 4: src = s4; Ksrc = 128; KP = 128; dstoff = 2 * o96 + 2 * o128; break;
        case 5: src = s5; Ksrc = 128; KP = 128; dstoff = 2 * o96 + 3 * o128; break;
        case 6: src = s6; Ksrc = 128; KP = 128; dstoff = 2 * o96 + 4 * o128; break;
        default: src = s7; Ksrc = 128; KP = 128; dstoff = 2 * o96 + 5 * o128; break;
    }
    int i = blockIdx.x * blockDim.x + threadIdx.x;
    if (i < 128 * KP) {
        int n = i / KP, k = i - n * KP;
        float v = (k < Ksrc) ? src[(size_t)k * DIMC + n] : 0.f;
        unsigned short hi = f2b(v);
        unsigned short lo = f2b(v - b2f(hi));
        whi[dstoff + i] = hi;
        wlo[dstoff + i] = lo;
    }
}

// ---------------- pad x: fp32 [N][78] -> fp32 [N][96] (zero-padded cols) ----------------

__global__ void k_pad_x(const float* __restrict__ x, float* __restrict__ x96, int N) {
    int i = blockIdx.x * blockDim.x + threadIdx.x;
    int r = i / 24, c4 = (i - r * 24) * 4;
    if (r >= N) return;
    float v[4];
#pragma unroll
    for (int j = 0; j < 4; ++j) { int k = c4 + j; v[j] = (k < FINC) ? x[(size_t)r * FINC + k] : 0.f; }
    *(float4*)(x96 + (size_t)r * 96 + c4) = make_float4(v[0], v[1], v[2], v[3]);
}

// ---------------- MFMA GEMM, COALESCED DMA staging ----------------
// 128-row block, 4 waves in 2x2 quadrants (wave w: rows wr=(w>>1)*64, cols wc=(w&1)*64).
// A (fp32 [N][KP]) per 32-K chunk: thread (r=tid>>3, u=tid&7), 4 passes of 32 rows:
//   source = row's 128B chunk, unit u^(r&7) (XOR WITHIN the row => line-coalesced:
//   each row-group of 8 lanes covers its row's 128B => 16x64B txns/inst, not 64x16B).
//   LDS = row-major [128][32] floats, linear in tid (DMA constraint).
// B (split bf16 [128][KP]) per chunk: thread (r=tid>>2, u=tid&3), 2 passes x 2 planes:
//   source unit u^((r>>1)&3) within row's 64B. LDS row-major [128][32] shorts.
// 8 DMA insts/chunk, double-buffered, vmcnt(8), raw barriers (R4-proven schedule).
// Frag reads are 2-way bank-aliased (free). A converted fp32->bf16 hi/lo in-register.
// MFMA (HW-verified r4/r5/r7): acc = mfma(b_frag, a_frag) -> C[row=..+lm][col=..+q*4+i].

template<int KP, bool STATS>
__launch_bounds__(256, 2)
__global__ void k_gemm_c(const float* __restrict__ A,
                         const unsigned short* __restrict__ Bhi,
                         const unsigned short* __restrict__ Blo,
                         const float* __restrict__ bias, const float* __restrict__ rowScale,
                         float* __restrict__ statsOut, float* __restrict__ C,
                         int N, int doRelu) {
    constexpr int NT = KP / 32;
    __shared__ float          ldsA[2][4096];       // [dbuf][128 rows x 32 f] row-major, unit-XOR
    __shared__ unsigned short ldsB[2][2][4096];    // [dbuf][hi,lo][128 rows x 32 h] row-major, unit-XOR
    __shared__ float sStats[256];
    const int tid = threadIdx.x;
    const int wave = tid >> 6, lane = tid & 63;
    const int lm = lane & 15, q = lane >> 4;
    const int wr = (wave >> 1) * 64, wc = (wave & 1) * 64;
    const int row0 = blockIdx.x * 128;

    const int au = tid & 7, ar = tid >> 3;         // A staging: unit, row-base (0..31)
    const int bu = tid & 3, br = tid >> 2;         // B staging: unit, row-base (0..63)

    auto stage = [&](int c, int d) {
        const int cb = c << 5;                     // chunk base (elems: floats for A, shorts for B)
#pragma unroll
        for (int p = 0; p < 4; ++p) {
            int r = p * 32 + ar;
            gld16(A + (size_t)(row0 + r) * KP + cb + ((au ^ (r & 7)) << 2),
                  &ldsA[d][(p * 256 + tid) << 2]);
        }
#pragma unroll
        for (int p = 0; p < 2; ++p) {
            int r = p * 64 + br;
            int so = cb + ((bu ^ ((r >> 1) & 3)) << 3);
            gld16(Bhi + (size_t)r * KP + so, &ldsB[d][0][(p * 256 + tid) << 3]);
            gld16(Blo + (size_t)r * KP + so, &ldsB[d][1][(p * 256 + tid) << 3]);
        }
    };

    f32x4 acc[4][4];
#pragma unroll
    for (int a = 0; a < 4; ++a)
#pragma unroll
        for (int b = 0; b < 4; ++b) acc[a][b] = (f32x4){0.f, 0.f, 0.f, 0.f};

    stage(0, 0);
#pragma unroll
    for (int t = 0; t < NT; ++t) {
        const int cur = t & 1;
        if (t + 1 < NT) {
            stage(t + 1, cur ^ 1);
            asm volatile("s_waitcnt vmcnt(8)" ::: "memory");   // chunk t's 8 DMA insts landed
        } else {
            asm volatile("s_waitcnt vmcnt(0)" ::: "memory");
        }
        __builtin_amdgcn_s_barrier();
        __builtin_amdgcn_sched_barrier(0);

        // A frags: rows wr+rt*16+lm, fp32 -> bf16 hi/lo in-register
        short8x ah[4], al[4];
#pragma unroll
        for (int rt = 0; rt < 4; ++rt) {
            int m = wr + rt * 16 + lm;
            float4 f0 = *(const float4*)&ldsA[cur][m * 32 + (((2 * q) ^ (m & 7)) << 2)];
            float4 f1 = *(const float4*)&ldsA[cur][m * 32 + ((((2 * q) + 1) ^ (m & 7)) << 2)];
            float ff[8] = {f0.x, f0.y, f0.z, f0.w, f1.x, f1.y, f1.z, f1.w};
#pragma unroll
            for (int j = 0; j < 8; ++j) {
                unsigned short h = f2b(ff[j]);
                ah[rt][j] = (short)h;
                al[rt][j] = (short)f2b(ff[j] - b2f(h));
            }
        }
#pragma unroll
        for (int ct = 0; ct < 4; ++ct) {
            int n = wc + ct * 16 + lm;
            int sl = n * 32 + ((q ^ ((n >> 1) & 3)) << 3);
            short8x bh = *(const short8x*)&ldsB[cur][0][sl];
            short8x bl = *(const short8x*)&ldsB[cur][1][sl];
#pragma unroll
            for (int rt = 0; rt < 4; ++rt) {
                acc[rt][ct] = __builtin_amdgcn_mfma_f32_16x16x32_bf16(bh, ah[rt], acc[rt][ct], 0, 0, 0);
                acc[rt][ct] = __builtin_amdgcn_mfma_f32_16x16x32_bf16(bh, al[rt], acc[rt][ct], 0, 0, 0);
                acc[rt][ct] = __builtin_amdgcn_mfma_f32_16x16x32_bf16(bl, ah[rt], acc[rt][ct], 0, 0, 0);
            }
        }
        __builtin_amdgcn_s_barrier();   // protect LDS bufs about to be overwritten
    }

    // epilogue: bias -> relu -> rowScale, fp32 float4 stores, optional column stats
    float cs[4][4], cq[4][4];
    if constexpr (STATS) {
#pragma unroll
        for (int a = 0; a < 4; ++a)
#pragma unroll
            for (int b = 0; b < 4; ++b) { cs[a][b] = 0.f; cq[a][b] = 0.f; }
    }

#pragma unroll
    for (int rt = 0; rt < 4; ++rt) {
        int grow = row0 + wr + rt * 16 + lm;
        if (grow < N) {
            float sc = rowScale ? rowScale[grow] : 1.f;
#pragma unroll
            for (int ct = 0; ct < 4; ++ct) {
                int nb = wc + ct * 16 + q * 4;
                float vv[4];
#pragma unroll
                for (int i = 0; i < 4; ++i) {
                    float v = acc[rt][ct][i];
                    if (bias) v += bias[nb + i];
                    if (doRelu) v = fmaxf(v, 0.f);
                    v *= sc;
                    vv[i] = v;
                    if constexpr (STATS) { cs[ct][i] += v; cq[ct][i] = fmaf(v, v, cq[ct][i]); }
                }
                *(float4*)(C + (size_t)grow * DIMC + nb) = make_float4(vv[0], vv[1], vv[2], vv[3]);
            }
        }
    }

    if constexpr (STATS) {
        sStats[tid] = 0.f;
        __syncthreads();
#pragma unroll
        for (int ct = 0; ct < 4; ++ct)
#pragma unroll
            for (int i = 0; i < 4; ++i) {
                float vs = cs[ct][i], vq = cq[ct][i];
#pragma unroll
                for (int o = 1; o < 16; o <<= 1) { vs += __shfl_xor(vs, o); vq += __shfl_xor(vq, o); }
                if (lm == 0) {
                    int colg = wc + ct * 16 + q * 4 + i;
                    atomicAdd(&sStats[colg], vs);
                    atomicAdd(&sStats[DIMC + colg], vq);
                }
            }
        __syncthreads();
        atomicAdd(&statsOut[tid], sStats[tid]);
    }
}

// ---------------- BN coefficients: sums -> (scale, shift) ----------------

__global__ void k_bn_coef(const float* __restrict__ bnsum, const float* __restrict__ gamma,
                          const float* __restrict__ beta, float* __restrict__ coef, float invN) {
    int c = threadIdx.x;  // 128
    float mu  = bnsum[c] * invN;
    float var = bnsum[128 + c] * invN - mu * mu;
    float inv = rsqrtf(var + 1e-5f);
    float s = gamma[c] * inv;
    coef[c] = s;
    coef[128 + c] = beta[c] - mu * s;
}

// ---- fold BN affine into next layer's W1: W'[n][k] = s[k]*w1[k][n], cvec[n] = sum_k t[k]*w1[k][n]

__global__ void k_fold_w(const float* __restrict__ w1, const float* __restrict__ coefL,
                         unsigned short* __restrict__ fwhi, unsigned short* __restrict__ fwlo,
                         float* __restrict__ cvec) {
    __shared__ float red[128];
    int n = blockIdx.x, k = threadIdx.x;
    float w = w1[(size_t)k * DIMC + n];
    float ws = w * coefL[k];
    unsigned short h = f2b(ws);
    fwhi[(size_t)n * DIMC + k] = h;
    fwlo[(size_t)n * DIMC + k] = f2b(ws - b2f(h));
    red[k] = w * coefL[DIMC + k];
    __syncthreads();
    for (int d = 64; d > 0; d >>= 1) { if (k < d) red[k] += red[k + d]; __syncthreads(); }
    if (k == 0) cvec[n] = red[0];
}

// ---------------- CSR gather aggregation (fp32, round-0 proven) ----------------

__global__ void k_gather_gcn(const float4* __restrict__ t, const int* __restrict__ rowptr,
                             const int* __restrict__ col, const float* __restrict__ dis,
                             const float4* __restrict__ bias, float4* __restrict__ out, int N) {
    int i = blockIdx.x * blockDim.x + threadIdx.x;
    int node = i >> 5, c4 = i & 31;
    if (node >= N) return;
    int s = rowptr[node], e = rowptr[node + 1];
    float4 acc = t[(size_t)node * 32 + c4];
    for (int k = s; k < e; ++k) {
        float4 v = t[(size_t)col[k] * 32 + c4];
        acc.x += v.x; acc.y += v.y; acc.z += v.z; acc.w += v.w;
    }
    float d = dis[node];
    float4 b = bias[c4];
    float4 o;
    o.x = fmaxf(acc.x * d + b.x, 0.f);
    o.y = fmaxf(acc.y * d + b.y, 0.f);
    o.z = fmaxf(acc.z * d + b.z, 0.f);
    o.w = fmaxf(acc.w * d + b.w, 0.f);
    out[(size_t)node * 32 + c4] = o;
}

__global__ void k_gather_gin(const float4* __restrict__ t, const int* __restrict__ rowptr,
                             const int* __restrict__ col, const float4* __restrict__ bias,
                             float4* __restrict__ out, int N) {
    int i = blockIdx.x * blockDim.x + threadIdx.x;
    int node = i >> 5, c4 = i & 31;
    if (node >= N) return;
    int s = rowptr[node], e = rowptr[node + 1];
    float4 acc = t[(size_t)node * 32 + c4];
    for (int k = s; k < e; ++k) {
        float4 v = t[(size_t)col[k] * 32 + c4];
        acc.x += v.x; acc.y += v.y; acc.z += v.z; acc.w += v.w;
    }
    float4 b = bias[c4];
    float4 o;
    o.x = fmaxf(acc.x + b.x, 0.f);
    o.y = fmaxf(acc.y + b.y, 0.f);
    o.z = fmaxf(acc.z + b.z, 0.f);
    o.w = fmaxf(acc.w + b.w, 0.f);
    out[(size_t)node * 32 + c4] = o;
}

// ---------------- segment max (fp32, round-0 proven) ----------------

__global__ void k_segmax_gin_all(const float* __restrict__ h0, const float* __restrict__ h1,
                                 const float* __restrict__ h2, const float* __restrict__ coef,
                                 const int* __restrict__ start, float* __restrict__ out) {
    int g = blockIdx.x, c = threadIdx.x;
    float s0 = coef[c],       t0 = coef[128 + c];
    float s1 = coef[256 + c], t1 = coef[384 + c];
    float s2 = coef[512 + c], t2 = coef[640 + c];
    int s = start[g], e = start[g + 1];
    float m0 = -INFINITY, m1 = -INFINITY, m2 = -INFINITY, mm = -INFINITY, me = -INFINITY;
    for (int n = s; n < e; ++n) {
        size_t idx = (size_t)n * DIMC + c;
        float a0 = fmaf(h0[idx], s0, t0);
        float a1 = fmaf(h1[idx], s1, t1);
        float a2 = fmaf(h2[idx], s2, t2);
        m0 = fmaxf(m0, a0); m1 = fmaxf(m1, a1); m2 = fmaxf(m2, a2);
        mm = fmaxf(mm, a0 * a1 * a2);
        me = fmaxf(me, a0 + a1 + a2);
    }
    size_t o = (size_t)g * REPW + c;
    out[o]            = m0;
    out[o + 1 * DIMC] = m1;
    out[o + 2 * DIMC] = m2;
    out[o + 3 * DIMC] = mm;
    out[o + 4 * DIMC] = me;
}

__global__ void k_segmax_gcn(const float* __restrict__ G1, const float* __restrict__ G2,
                             const int* __restrict__ start, float* __restrict__ out) {
    int g = blockIdx.x, c = threadIdx.x;
    int s = start[g], e = start[g + 1];
    float m1 = -INFINITY, m2 = -INFINITY, ma = -INFINITY, mm = -INFINITY;
    for (int n = s; n < e; ++n) {
        float a = G1[(size_t)n * DIMC + c], b = G2[(size_t)n * DIMC + c];
        m1 = fmaxf(m1, a); m2 = fmaxf(m2, b);
        ma = fmaxf(ma, a + b); mm = fmaxf(mm, a * b);
    }
    size_t o = (size_t)g * REPW + c;
    out[o + 5 * DIMC] = m1;
    out[o + 6 * DIMC] = m2;
    out[o + 7 * DIMC] = ma;
    out[o + 8 * DIMC] = mm;
}

// ---------------- launch ----------------

extern "C" void kernel_launch(void* const* d_in, const int* in_sizes, int n_in,
                              void* d_out, int out_size, void* d_ws, size_t ws_size,
                              hipStream_t stream) {
    const float* x       = (const float*)d_in[0];
    const int*   ei      = (const int*)d_in[1];
    const int*   batch   = (const int*)d_in[2];
    const float* gcn1_W  = (const float*)d_in[4];
    const float* gcn1_b  = (const float*)d_in[5];
    const float* gcn2_W  = (const float*)d_in[6];
    const float* gcn2_b  = (const float*)d_in[7];
    const float* gin0_w1 = (const float*)d_in[8];
    const float* gin0_b1 = (const float*)d_in[9];
    const float* gin0_w2 = (const float*)d_in[10];
    const float* gin0_b2 = (const float*)d_in[11];
    const float* gin_w1  = (const float*)d_in[12];
    const float* gin_b1  = (const float*)d_in[13];
    const float* gin_w2  = (const float*)d_in[14];
    const float* gin_b2  = (const float*)d_in[15];
    const float* bn_g    = (const float*)d_in[16];
    const float* bn_b    = (const float*)d_in[17];
    float* out = (float*)d_out;

    const int N = in_sizes[0] / FINC;   // 100000
    const int E = in_sizes[1] / 2;      // 400000
    const int G = out_size / REPW;      // 2500
    const int* srcv = ei;
    const int* dstv = ei + E;

    // Workspace (~261 MB, proven-safe footprint). x96 (fp32 padded x, 38.4 MB)
    // aliases h1 (disjoint lifetimes: x dead before h1 first written).
    // GEMM A-input DMA may read up to 128 rows past N; all A-input buffers
    // (x96-in-h1, bufZ, h0, h1) are followed by other ws allocations -> in-bounds.
    char* ws = (char*)d_ws;
    size_t off = 0;
    auto alloc = [&](size_t bytes) { char* p = ws + off; off += (bytes + 255) & ~(size_t)255; return p; };
    int*   cnt     = (int*)alloc((size_t)N * 4);
    int*   rowptr  = (int*)alloc(((size_t)N + 1) * 4);
    int*   cursor  = (int*)alloc((size_t)N * 4);
    int*   col     = (int*)alloc((size_t)E * 4);
    float* dis     = (float*)alloc((size_t)N * 4);
    float* bnsum   = (float*)alloc(768 * 4);
    float* coef    = (float*)alloc(768 * 4);
    float* cvec    = (float*)alloc(128 * 4);
    int*   start   = (int*)alloc(((size_t)G + 1) * 4);
    int*   tileSum = (int*)alloc(256 * 4);
    int*   tileOff = (int*)alloc(256 * 4);
    const size_t o96 = (size_t)128 * 96, o128 = (size_t)128 * 128;
    const size_t wtElems = 2 * o96 + 6 * o128;
    unsigned short* whi  = (unsigned short*)alloc(wtElems * 2);
    unsigned short* wlo  = (unsigned short*)alloc(wtElems * 2);
    unsigned short* fwhi = (unsigned short*)alloc(o128 * 2);
    unsigned short* fwlo = (unsigned short*)alloc(o128 * 2);
    const size_t fbytes = (size_t)N * DIMC * 4;
    float* bufT = (float*)alloc(fbytes);
    float* bufZ = (float*)alloc(fbytes);
    float* h0   = (float*)alloc(fbytes);
    float* h1   = (float*)alloc(fbytes);   // hosts x96 early
    float* h2   = (float*)alloc(fbytes);
    float* x96  = h1;                      // N*96*4 = 38.4 MB (+DMA overrun) <= 51.2 MB
    (void)ws_size; (void)n_in;

    const size_t woff[8] = {0, o96, 2 * o96, 2 * o96 + o128, 2 * o96 + 2 * o128,
                            2 * o96 + 3 * o128, 2 * o96 + 4 * o128, 2 * o96 + 5 * o128};
    // order: gcn1, gin0_w1, gcn2, gin0_w2, gin_w1[0], gin_w1[1], gin_w2[0], gin_w2[1]

    const int T = 256;
    auto cdiv = [](long a, long b) { return (int)((a + b - 1) / b); };
    const int gemmGrid = cdiv(N, 128);
    const int gatherGrid = cdiv((long)N * 32, T);
    const int nTiles = cdiv(N, SCAN_TILE);
    const float invN = 1.0f / (float)N;

    // ---- CSR build + norms + graph bounds + weight split + x pad ----
    k_fill_int<<<cdiv(N, T), T, 0, stream>>>(cnt, 0, N);
    k_count<<<cdiv(E, T), T, 0, stream>>>(dstv, cnt, E);
    k_tilesum<<<nTiles, T, 0, stream>>>(cnt, tileSum, N);
    k_tilescan<<<1, T, 0, stream>>>(tileSum, tileOff, rowptr, nTiles, N);
    k_tileemit<<<nTiles, T, 0, stream>>>(cnt, tileOff, rowptr, cursor, dis, N);
    k_scatter<<<cdiv(E, T), T, 0, stream>>>(srcv, dstv, cursor, col, E);
    k_bounds<<<cdiv(G + 1, T), T, 0, stream>>>(batch, start, N, G);
    k_fill<<<3, T, 0, stream>>>(bnsum, 0.f, 768);
    {
        dim3 g(64, 8);
        k_cvt_w<<<g, T, 0, stream>>>(gcn1_W, gin0_w1, gcn2_W, gin0_w2,
                                     gin_w1, gin_w1 + o128, gin_w2, gin_w2 + o128, whi, wlo);
    }
    k_pad_x<<<cdiv((long)N * 24, T), T, 0, stream>>>(x, x96, N);

    // ---- GCN branch ----
    k_gemm_c<96, false><<<gemmGrid, T, 0, stream>>>(x96, whi + woff[0], wlo + woff[0],
                                                    nullptr, dis, nullptr, bufT, N, 0);
    k_gather_gcn<<<gatherGrid, T, 0, stream>>>((const float4*)bufT, rowptr, col, dis,
                                               (const float4*)gcn1_b, (float4*)bufZ, N);   // g1
    k_gemm_c<128, false><<<gemmGrid, T, 0, stream>>>(bufZ, whi + woff[2], wlo + woff[2],
                                                     nullptr, dis, nullptr, bufT, N, 0);
    k_gather_gcn<<<gatherGrid, T, 0, stream>>>((const float4*)bufT, rowptr, col, dis,
                                               (const float4*)gcn2_b, (float4*)h0, N);     // g2
    k_segmax_gcn<<<G, DIMC, 0, stream>>>(bufZ, h0, start, out);                            // groups 5..8

    // ---- GIN layer 0 ----
    k_gemm_c<96, false><<<gemmGrid, T, 0, stream>>>(x96, whi + woff[1], wlo + woff[1],
                                                    nullptr, nullptr, nullptr, bufT, N, 0);
    k_gather_gin<<<gatherGrid, T, 0, stream>>>((const float4*)bufT, rowptr, col,
                                               (const float4*)gin0_b1, (float4*)bufZ, N);
    k_gemm_c<128, true><<<gemmGrid, T, 0, stream>>>(bufZ, whi + woff[3], wlo + woff[3],
                                                    gin0_b2, nullptr, bnsum, h0, N, 1);
    k_bn_coef<<<1, DIMC, 0, stream>>>(bnsum, bn_g, bn_b, coef, invN);
    k_fold_w<<<DIMC, DIMC, 0, stream>>>(gin_w1, coef, fwhi, fwlo, cvec);

    // ---- GIN layer 1 (BN folded into weights; x96 in h1 dead from here) ----
    k_gemm_c<128, false><<<gemmGrid, T, 0, stream>>>(h0, fwhi, fwlo,
                                                     cvec, nullptr, nullptr, bufT, N, 0);
    k_gather_gin<<<gatherGrid, T, 0, stream>>>((const float4*)bufT, rowptr, col,
                                               (const float4*)gin_b1, (float4*)bufZ, N);
    k_gemm_c<128, true><<<gemmGrid, T, 0, stream>>>(bufZ, whi + woff[6], wlo + woff[6],
                                                    gin_b2, nullptr, bnsum + 256, h1, N, 1);
    k_bn_coef<<<1, DIMC, 0, stream>>>(bnsum + 256, bn_g + DIMC, bn_b + DIMC, coef + 256, invN);
    k_fold_w<<<DIMC, DIMC, 0, stream>>>(gin_w1 + o128, coef + 256, fwhi, fwlo, cvec);

    // ---- GIN layer 2 ----
    k_gemm_c<128, false><<<gemmGrid, T, 0, stream>>>(h1, fwhi, fwlo,
                                                     cvec, nullptr, nullptr, bufT, N, 0);
    k_gather_gin<<<gatherGrid, T, 0, stream>>>((const float4*)bufT, rowptr, col,
                                               (const float4*)(gin_b1 + DIMC), (float4*)bufZ, N);
    k_gemm_c<128, true><<<gemmGrid, T, 0, stream>>>(bufZ, whi + woff[7], wlo + woff[7],
                                                    gin_b2 + DIMC, nullptr, bnsum + 512, h2, N, 1);
    k_bn_coef<<<1, DIMC, 0, stream>>>(bnsum + 512, bn_g + 2 * DIMC, bn_b + 2 * DIMC, coef + 512, invN);

    k_segmax_gin_all<<<G, DIMC, 0, stream>>>(h0, h1, h2, coef, start, out);                // groups 0..4
}